// Round 2
// baseline (107.181 us; speedup 1.0000x reference)
//
#include <hip/hip_runtime.h>
#include <math.h>

#define NYX 192
#define NNODE 193
#define L_NODES (193*193)
#define NPAIR 11
#define NB 2
#define NCH 12
#define NELEM (NB*NCH*NYX*NYX)   /* 884736 */
#define NPIX  (NB*NYX*NYX)       /* 73728  */
#define LN2f 0.6931471805599453f

/* ws layout (bytes):
   [0, 7077888)            float2 sb[NELEM]      (sig, bce) per element
   [7077888, 7225344)      u16 pack[NPIX]        12 label bits per pixel
   [7225344, 7225696)      float red[22*4]       reduction groups        */
#define SB_OFF   0
#define PACK_OFF 7077888
#define RED_OFF  7225344

__global__ __launch_bounds__(256) void sdice_elem(const float* __restrict__ pred,
                                                  const float* __restrict__ labels,
                                                  float2* __restrict__ sb)
{
    const int i = (blockIdx.x * 256 + threadIdx.x) * 4;   /* NELEM % 4 == 0, grid exact */
    const float4 x4 = *reinterpret_cast<const float4*>(pred + i);
    const float4 y4 = *reinterpret_cast<const float4*>(labels + i);
    const float xs[4] = {x4.x, x4.y, x4.z, x4.w};
    const float ys[4] = {y4.x, y4.y, y4.z, y4.w};
    float s[4], bb[4];
    #pragma unroll
    for (int k = 0; k < 4; ++k) {
        const float x = xs[k], y = ys[k];
        s[k]  = 1.0f / (1.0f + expf(-x));
        bb[k] = fmaxf(x, 0.0f) - x * y + log1pf(expf(-fabsf(x)));
    }
    float4* o = reinterpret_cast<float4*>(sb + i);
    o[0] = make_float4(s[0], bb[0], s[1], bb[1]);
    o[1] = make_float4(s[2], bb[2], s[3], bb[3]);
}

__global__ __launch_bounds__(256) void sdice_pack(const float* __restrict__ labels,
                                                  unsigned short* __restrict__ pack)
{
    const int p = blockIdx.x * 256 + threadIdx.x;         /* NPIX = 288*256 exact */
    const int b  = p / (NYX * NYX);
    const int yx = p - b * (NYX * NYX);
    unsigned v = 0;
    #pragma unroll
    for (int ch = 0; ch < NCH; ++ch)
        v |= ((unsigned)labels[(size_t)(b * NCH + ch) * NYX * NYX + yx]) << ch;
    pack[p] = (unsigned short)v;
}

__global__ __launch_bounds__(256) void sdice_node(const float2* __restrict__ sb,
                                                  const unsigned short* __restrict__ pack,
                                                  const float* __restrict__ area,
                                                  float* __restrict__ red)
{
    const int pair = blockIdx.z;
    const int b    = blockIdx.y;
    const int l    = blockIdx.x * blockDim.x + threadIdx.x;

    float num = 0.f, den = 0.f, bces = 0.f, cnt = 0.f;

    if (l < L_NODES) {
        const int j  = l / NNODE;
        const int ix = l - j * NNODE;

        unsigned m[4];
        float up[8], bc[8];
        #pragma unroll
        for (int ky = 0; ky < 2; ++ky) {
            const int y = j - 1 + ky;
            #pragma unroll
            for (int kx = 0; kx < 2; ++kx) {
                const int x = ix - 1 + kx;
                const bool inb = ((unsigned)y < NYX) && ((unsigned)x < NYX);
                m[ky * 2 + kx] = inb ? (unsigned)pack[(size_t)(b * NYX + y) * NYX + x] : 0u;
                #pragma unroll
                for (int c = 0; c < 2; ++c) {
                    const int k = c * 4 + ky * 2 + kx;
                    float2 v = make_float2(0.0f, LN2f);
                    if (inb)
                        v = sb[((size_t)(b * NCH + pair + c) * NYX + y) * NYX + x];
                    up[k] = v.x;
                    bc[k] = v.y;
                }
            }
        }

        int byte = 0;
        float d2 = 0.f;
        #pragma unroll
        for (int k = 0; k < 8; ++k) {
            const int bit = (m[k & 3] >> (pair + (k >> 2))) & 1;
            byte |= bit << k;
            const float d = up[k] - (float)bit;
            d2 += d * d;
        }
        const float w_lab = 1.0f - sqrtf(d2) * (1.0f / 16.0f);
        const float la = area[byte];
        num = w_lab * la;
        den = la;
        if (byte == 0 || byte == 255) {
            cnt = 1.f;
            bces = ((bc[0] + bc[1]) + (bc[2] + bc[3])) + ((bc[4] + bc[5]) + (bc[6] + bc[7]));
        }
    }

    #pragma unroll
    for (int off = 32; off > 0; off >>= 1) {
        num  += __shfl_down(num, off);
        den  += __shfl_down(den, off);
        bces += __shfl_down(bces, off);
        cnt  += __shfl_down(cnt, off);
    }
    __shared__ float sred[4][4];
    const int lane = threadIdx.x & 63;
    const int wid  = threadIdx.x >> 6;
    if (lane == 0) { sred[wid][0] = num; sred[wid][1] = den; sred[wid][2] = bces; sred[wid][3] = cnt; }
    __syncthreads();
    if (threadIdx.x == 0) {
        float n = 0, d = 0, bcs = 0, ct = 0;
        #pragma unroll
        for (int w = 0; w < 4; ++w) { n += sred[w][0]; d += sred[w][1]; bcs += sred[w][2]; ct += sred[w][3]; }
        float* g = red + (size_t)(pair * NB + b) * 4;
        atomicAdd(g + 0, n);
        atomicAdd(g + 1, d);
        atomicAdd(g + 2, bcs);
        atomicAdd(g + 3, ct);
    }
}

__global__ void sdice_final(const float* __restrict__ red,
                            const float* __restrict__ area,
                            float* __restrict__ out)
{
    if (threadIdx.x == 0 && blockIdx.x == 0) {
        const float a1 = area[1];   /* pred_byte == 1 everywhere (strict '>' in fori_loop) */
        float dice_sum = 0.f, vol_sum = 0.f;
        for (int b = 0; b < NB; ++b) {
            float numb = 0.f, denb = 0.f, volb = 0.f;
            for (int p = 0; p < NPAIR; ++p) {
                const float* g = red + (size_t)(p * NB + b) * 4;
                numb += 2.0f * g[0];
                denb += g[1] + (float)L_NODES * a1;
                volb += g[2] / (8.0f * g[3]);
            }
            dice_sum += 1.0f - (numb + 0.001f) / (denb + 0.001f);
            vol_sum  += volb;
        }
        out[0] = dice_sum / (float)NB + vol_sum / (float)NB;
    }
}

extern "C" void kernel_launch(void* const* d_in, const int* in_sizes, int n_in,
                              void* d_out, int out_size, void* d_ws, size_t ws_size,
                              hipStream_t stream) {
    const float* pred   = (const float*)d_in[0];
    const float* labels = (const float*)d_in[1];
    const float* area   = (const float*)d_in[2];
    float* out = (float*)d_out;
    char* ws   = (char*)d_ws;

    float2*         sb   = (float2*)(ws + SB_OFF);
    unsigned short* pck  = (unsigned short*)(ws + PACK_OFF);
    float*          red  = (float*)(ws + RED_OFF);

    hipMemsetAsync(red, 0, NPAIR * NB * 4 * sizeof(float), stream);

    sdice_elem<<<dim3(NELEM / 4 / 256), dim3(256), 0, stream>>>(pred, labels, sb);
    sdice_pack<<<dim3(NPIX / 256), dim3(256), 0, stream>>>(labels, pck);

    dim3 grid((L_NODES + 255) / 256, NB, NPAIR);
    sdice_node<<<grid, dim3(256), 0, stream>>>(sb, pck, area, red);
    sdice_final<<<1, 64, 0, stream>>>(red, area, out);
}

// Round 3
// 37.273 us; speedup vs baseline: 2.8756x; 2.8756x over previous
//
#include <hip/hip_runtime.h>
#include <math.h>

#define NYX 192
#define NNODE 193
#define L_NODES (193*193)
#define NPAIR 11
#define NB 2
#define NCH 12
#define NGRP (NPAIR*NB)          /* 22 reduction groups            */
#define NBLK 146                 /* ceil(37249/256) node blocks    */
#define NELEM (NB*NCH*NYX*NYX)   /* 884736 */
#define NPIX  (NB*NYX*NYX)       /* 73728  */
#define LN2f 0.6931471805599453f

/* ws layout (bytes):
   [0, 7077888)            float2 sb[NELEM]        (sig, bce) per element
   [7077888, 7225344)      u16 pack[NPIX]          12 label bits per pixel
   [7225344, 7276736)      float4 partials[22*146] per-block partial sums  */
#define SB_OFF   0
#define PACK_OFF 7077888
#define PART_OFF 7225344

__global__ __launch_bounds__(256) void sdice_elem(const float* __restrict__ pred,
                                                  const float* __restrict__ labels,
                                                  float2* __restrict__ sb)
{
    const int i = (blockIdx.x * 256 + threadIdx.x) * 4;   /* NELEM % 1024 == 0 */
    const float4 x4 = *reinterpret_cast<const float4*>(pred + i);
    const float4 y4 = *reinterpret_cast<const float4*>(labels + i);
    const float xs[4] = {x4.x, x4.y, x4.z, x4.w};
    const float ys[4] = {y4.x, y4.y, y4.z, y4.w};
    float s[4], bb[4];
    #pragma unroll
    for (int k = 0; k < 4; ++k) {
        const float x = xs[k], y = ys[k];
        s[k]  = 1.0f / (1.0f + expf(-x));
        bb[k] = fmaxf(x, 0.0f) - x * y + log1pf(expf(-fabsf(x)));
    }
    float4* o = reinterpret_cast<float4*>(sb + i);
    o[0] = make_float4(s[0], bb[0], s[1], bb[1]);
    o[1] = make_float4(s[2], bb[2], s[3], bb[3]);
}

__global__ __launch_bounds__(256) void sdice_pack(const float* __restrict__ labels,
                                                  unsigned short* __restrict__ pack)
{
    const int p = blockIdx.x * 256 + threadIdx.x;         /* NPIX = 288*256 exact */
    const int b  = p / (NYX * NYX);
    const int yx = p - b * (NYX * NYX);
    unsigned v = 0;
    #pragma unroll
    for (int ch = 0; ch < NCH; ++ch)
        v |= ((unsigned)labels[(size_t)(b * NCH + ch) * NYX * NYX + yx]) << ch;
    pack[p] = (unsigned short)v;
}

__global__ __launch_bounds__(256) void sdice_node(const float2* __restrict__ sb,
                                                  const unsigned short* __restrict__ pack,
                                                  const float* __restrict__ area,
                                                  float4* __restrict__ partials)
{
    const int pair = blockIdx.z;
    const int b    = blockIdx.y;
    const int l    = blockIdx.x * blockDim.x + threadIdx.x;

    float num = 0.f, den = 0.f, bces = 0.f, cnt = 0.f;

    if (l < L_NODES) {
        const int j  = l / NNODE;
        const int ix = l - j * NNODE;

        unsigned m[4];
        float up[8], bc[8];
        #pragma unroll
        for (int ky = 0; ky < 2; ++ky) {
            const int y = j - 1 + ky;
            #pragma unroll
            for (int kx = 0; kx < 2; ++kx) {
                const int x = ix - 1 + kx;
                const bool inb = ((unsigned)y < NYX) && ((unsigned)x < NYX);
                m[ky * 2 + kx] = inb ? (unsigned)pack[(size_t)(b * NYX + y) * NYX + x] : 0u;
                #pragma unroll
                for (int c = 0; c < 2; ++c) {
                    const int k = c * 4 + ky * 2 + kx;
                    float2 v = make_float2(0.0f, LN2f);
                    if (inb)
                        v = sb[((size_t)(b * NCH + pair + c) * NYX + y) * NYX + x];
                    up[k] = v.x;
                    bc[k] = v.y;
                }
            }
        }

        int byte = 0;
        float d2 = 0.f;
        #pragma unroll
        for (int k = 0; k < 8; ++k) {
            const int bit = (m[k & 3] >> (pair + (k >> 2))) & 1;
            byte |= bit << k;
            const float d = up[k] - (float)bit;
            d2 += d * d;
        }
        const float w_lab = 1.0f - sqrtf(d2) * (1.0f / 16.0f);
        const float la = area[byte];
        num = w_lab * la;
        den = la;
        if (byte == 0 || byte == 255) {
            cnt = 1.f;
            bces = ((bc[0] + bc[1]) + (bc[2] + bc[3])) + ((bc[4] + bc[5]) + (bc[6] + bc[7]));
        }
    }

    #pragma unroll
    for (int off = 32; off > 0; off >>= 1) {
        num  += __shfl_down(num, off);
        den  += __shfl_down(den, off);
        bces += __shfl_down(bces, off);
        cnt  += __shfl_down(cnt, off);
    }
    __shared__ float sred[4][4];
    const int lane = threadIdx.x & 63;
    const int wid  = threadIdx.x >> 6;
    if (lane == 0) { sred[wid][0] = num; sred[wid][1] = den; sred[wid][2] = bces; sred[wid][3] = cnt; }
    __syncthreads();
    if (threadIdx.x == 0) {
        float n = 0, d = 0, bcs = 0, ct = 0;
        #pragma unroll
        for (int w = 0; w < 4; ++w) { n += sred[w][0]; d += sred[w][1]; bcs += sred[w][2]; ct += sred[w][3]; }
        /* NON-atomic per-block partial: group = pair*NB + b */
        partials[(size_t)(pair * NB + b) * NBLK + blockIdx.x] = make_float4(n, d, bcs, ct);
    }
}

__global__ __launch_bounds__(256) void sdice_final(const float4* __restrict__ partials,
                                                   const float* __restrict__ area,
                                                   float* __restrict__ out)
{
    __shared__ float gs[NGRP][4];
    const int wid  = threadIdx.x >> 6;
    const int lane = threadIdx.x & 63;

    for (int g = wid; g < NGRP; g += 4) {
        float n = 0.f, d = 0.f, bc = 0.f, ct = 0.f;
        for (int i = lane; i < NBLK; i += 64) {
            const float4 v = partials[(size_t)g * NBLK + i];
            n += v.x; d += v.y; bc += v.z; ct += v.w;
        }
        #pragma unroll
        for (int off = 32; off > 0; off >>= 1) {
            n  += __shfl_down(n, off);
            d  += __shfl_down(d, off);
            bc += __shfl_down(bc, off);
            ct += __shfl_down(ct, off);
        }
        if (lane == 0) { gs[g][0] = n; gs[g][1] = d; gs[g][2] = bc; gs[g][3] = ct; }
    }
    __syncthreads();
    if (threadIdx.x == 0) {
        const float a1 = area[1];   /* pred_byte == 1 everywhere (strict '>' in fori_loop) */
        float dice_sum = 0.f, vol_sum = 0.f;
        for (int b = 0; b < NB; ++b) {
            float numb = 0.f, denb = 0.f, volb = 0.f;
            for (int p = 0; p < NPAIR; ++p) {
                const int g = p * NB + b;
                numb += 2.0f * gs[g][0];
                denb += gs[g][1] + (float)L_NODES * a1;
                volb += gs[g][2] / (8.0f * gs[g][3]);
            }
            dice_sum += 1.0f - (numb + 0.001f) / (denb + 0.001f);
            vol_sum  += volb;
        }
        out[0] = dice_sum / (float)NB + vol_sum / (float)NB;
    }
}

extern "C" void kernel_launch(void* const* d_in, const int* in_sizes, int n_in,
                              void* d_out, int out_size, void* d_ws, size_t ws_size,
                              hipStream_t stream) {
    const float* pred   = (const float*)d_in[0];
    const float* labels = (const float*)d_in[1];
    const float* area   = (const float*)d_in[2];
    float* out = (float*)d_out;
    char* ws   = (char*)d_ws;

    float2*         sb   = (float2*)(ws + SB_OFF);
    unsigned short* pck  = (unsigned short*)(ws + PACK_OFF);
    float4*         part = (float4*)(ws + PART_OFF);

    sdice_elem<<<dim3(NELEM / 4 / 256), dim3(256), 0, stream>>>(pred, labels, sb);
    sdice_pack<<<dim3(NPIX / 256), dim3(256), 0, stream>>>(labels, pck);

    dim3 grid(NBLK, NB, NPAIR);
    sdice_node<<<grid, dim3(256), 0, stream>>>(sb, pck, area, part);
    sdice_final<<<1, 256, 0, stream>>>(part, area, out);
}